// Round 21
// baseline (255.880 us; speedup 1.0000x reference)
//
#include <hip/hip_runtime.h>

#define B_   8
#define C_   96
#define H_   160
#define W_   320
#define ND   9
#define NDD  81
#define TH   16
#define TW   32                 // 8 px/thread
#define KC   4                  // channels per chunk
#define NCH  24
#define F2ROWS 18
#define F2STRIDE 44             // 40 payload + 4 pad cols (2-way bank aliasing only)
#define F2PLANE (F2ROWS*F2STRIDE)   // 792 dw per channel
#define BUFW (KC*F2PLANE)           // 3168 dw = 12672 B
#define LDSWORDS 6656               // 26624 B (R14 champion size): ~3 blocks/CU, no spill

#define NBLK 800                // persistent: 3 jobs/block, all co-resident, 1 convoy
#define NJOB 2400

#define AS1 __attribute__((address_space(1)))
#define AS3 __attribute__((address_space(3)))

__device__ __forceinline__ void gld16(const float* gp, float* lp) {
    __builtin_amdgcn_global_load_lds((const AS1 float*)gp,
                                     (AS3 float*)(unsigned long long)lp, 16, 0, 0);
}

__global__ __launch_bounds__(192, 2)
void corr_kernel(const float* __restrict__ f1g,
                 const float* __restrict__ f2g,
                 float* __restrict__ out)
{
    __shared__ float lds[LDSWORDS];

    const int tid  = threadIdx.x;
    const int wave = tid >> 6;
    const int lane = tid & 63;
    const int row  = lane >> 2;         // 0..15
    const int colb = (lane & 3) << 3;   // 0,8,16,24
    const int HWi  = H_ * W_;

    // tile-invariant compute-side read bases
    const int o0 = (row + wave) * F2STRIDE + colb;

#pragma unroll 1
    for (int job = blockIdx.x; job < NJOB; job += NBLK) {
        // XCD-affine job decode (identical mapping to R14; job%8 == bid%8)
        const int ebid = (job & 7) * 300 + (job >> 3);
        const int b    = ebid / 300;
        const int t3   = ebid - b * 300;
        const int g    = t3 % 3;            // dh = 3g + wave
        const int tile = t3 / 3;
        const int by   = tile / 10, bx = tile - by * 10;
        const int x0 = bx * TW, y0 = by * TH;
        const int r0   = y0 + 3 * g - 4;

        const float* f1b = f1g + (size_t)b * C_ * HWi;
        const float* f2b = f2g + (size_t)b * C_ * HWi;
        const float* f1p = f1b + (y0 + row) * W_ + x0 + colb;

        // f2 staging maps (seg s -> lds dw 4s; r=s/11, c4=s%11; c4==10 pad)
        int soW, soT; bool ppW, ppT;
        {
            int s  = (wave << 6) + lane;
            int r  = s / 11, c4 = s - 11 * r;
            int gy = r0 + r, gx = x0 - 4 + (c4 << 2);
            ppW = (c4 < 10) & (gy >= 0) & (gy < H_) & (gx >= 0) & (gx <= W_ - 4);
            soW = gy * W_ + gx;
            s  = 192 + lane;
            r  = s / 11; c4 = s - 11 * r;
            gy = r0 + r; gx = x0 - 4 + (c4 << 2);
            ppT = (wave == 2) & (lane < 6) & (c4 < 10) &
                  (gy >= 0) & (gy < H_) & (gx >= 0) & (gx <= W_ - 4);
            soT = gy * W_ + gx;
        }
        const int partoff = wave << 8;

        auto stage = [&](int cb, int bufb) {
#pragma unroll
            for (int c = 0; c < KC; ++c) {
                const float* gsrc = f2b + (cb + c) * HWi;
                float* l = &lds[bufb + c * F2PLANE];
                if (ppW) gld16(gsrc + soW, l + partoff);
                if (ppT) gld16(gsrc + soT, l + 768);
            }
        };

        // per-job LDS zero: stale payload from the previous tile would leak
        // into slots whose predicate is now false. Barrier-bracketed.
        __syncthreads();
        for (int t = tid; t < LDSWORDS; t += 192) lds[t] = 0.f;
        __syncthreads();
        stage(0, 0);                          // chunk 0 -> buf 0

        // ---- accumulators ----
        float4 accA0, accA1, accA2, accA3, accA4, accA5, accA6, accA7, accA8;
        float4 accB0, accB1, accB2, accB3, accB4, accB5, accB6, accB7, accB8;
        accA0=accA1=accA2=accA3=accA4=accA5=accA6=accA7=accA8 = make_float4(0.f,0.f,0.f,0.f);
        accB0=accB1=accB2=accB3=accB4=accB5=accB6=accB7=accB8 = make_float4(0.f,0.f,0.f,0.f);
        float4 PA0, PA1, PA2, PA3, PB0, PB1, PB2, PB3;

#define F1LOAD(cb) {                                              \
        PA0 = *(const float4*)(f1p + (cb) * HWi);                 \
        PB0 = *(const float4*)(f1p + (cb) * HWi + 4);             \
        PA1 = *(const float4*)(f1p + ((cb)+1) * HWi);             \
        PB1 = *(const float4*)(f1p + ((cb)+1) * HWi + 4);         \
        PA2 = *(const float4*)(f1p + ((cb)+2) * HWi);             \
        PB2 = *(const float4*)(f1p + ((cb)+2) * HWi + 4);         \
        PA3 = *(const float4*)(f1p + ((cb)+3) * HWi);             \
        PB3 = *(const float4*)(f1p + ((cb)+3) * HWi + 4); }

#define STEPD(A, P, e0, e1, e2, e3)                          \
        A.x = fmaf(P.x, e0, A.x);                            \
        A.y = fmaf(P.y, e1, A.y);                            \
        A.z = fmaf(P.z, e2, A.z);                            \
        A.w = fmaf(P.w, e3, A.w);

#define COMPC(c, RB, PA, PB) {                                                    \
        const float4 q0 = *(const float4*)&lds[(RB) + c * F2PLANE + o0];          \
        const float4 q1 = *(const float4*)&lds[(RB) + c * F2PLANE + o0 + 4];      \
        const float4 q2 = *(const float4*)&lds[(RB) + c * F2PLANE + o0 + 8];      \
        const float4 q3 = *(const float4*)&lds[(RB) + c * F2PLANE + o0 + 12];     \
        const float w[16] = {q0.x,q0.y,q0.z,q0.w,q1.x,q1.y,q1.z,q1.w,            \
                             q2.x,q2.y,q2.z,q2.w,q3.x,q3.y,q3.z,q3.w};           \
        STEPD(accA0, PA, w[0], w[1], w[2], w[3])                                  \
        STEPD(accB0, PB, w[4], w[5], w[6], w[7])                                  \
        STEPD(accA1, PA, w[1], w[2], w[3], w[4])                                  \
        STEPD(accB1, PB, w[5], w[6], w[7], w[8])                                  \
        STEPD(accA2, PA, w[2], w[3], w[4], w[5])                                  \
        STEPD(accB2, PB, w[6], w[7], w[8], w[9])                                  \
        STEPD(accA3, PA, w[3], w[4], w[5], w[6])                                  \
        STEPD(accB3, PB, w[7], w[8], w[9], w[10])                                 \
        STEPD(accA4, PA, w[4], w[5], w[6], w[7])                                  \
        STEPD(accB4, PB, w[8], w[9], w[10], w[11])                                \
        STEPD(accA5, PA, w[5], w[6], w[7], w[8])                                  \
        STEPD(accB5, PB, w[9], w[10], w[11], w[12])                               \
        STEPD(accA6, PA, w[6], w[7], w[8], w[9])                                  \
        STEPD(accB6, PB, w[10], w[11], w[12], w[13])                              \
        STEPD(accA7, PA, w[7], w[8], w[9], w[10])                                 \
        STEPD(accB7, PB, w[11], w[12], w[13], w[14])                              \
        STEPD(accA8, PA, w[8], w[9], w[10], w[11])                                \
        STEPD(accB8, PB, w[12], w[13], w[14], w[15])                              \
    }
#define CHUNK(RB) COMPC(0,RB,PA0,PB0) COMPC(1,RB,PA1,PB1) \
                  COMPC(2,RB,PA2,PB2) COMPC(3,RB,PA3,PB3)

#pragma unroll 1
        for (int k = 0; k < NCH; ++k) {
            __syncthreads();                  // chunk-k DMA drained (issued 1 chunk ago)
            F1LOAD(KC * k)                    // f1 globals BEFORE next DMAs (in-order vmcnt)
            if (k + 1 < NCH) stage(KC * (k + 1), ((k + 1) & 1) * BUFW);
            __builtin_amdgcn_sched_barrier(0);
            CHUNK((k & 1) * BUFW)
        }

        // ---- epilogue: dh = 3g + wave ----
        const int dh = 3 * g + wave;
        const int gy = y0 + row;
        const int gx = x0 + colb;
#define STORED(d) {                                                                 \
        float* op_ = out + (size_t)((b * NDD + dh * ND + d) * H_ + gy) * W_ + gx;   \
        *(float4*)op_ = accA##d;                                                    \
        *(float4*)(op_ + 4) = accB##d; }
        STORED(0) STORED(1) STORED(2) STORED(3) STORED(4)
        STORED(5) STORED(6) STORED(7) STORED(8)
    }
}

extern "C" void kernel_launch(void* const* d_in, const int* in_sizes, int n_in,
                              void* d_out, int out_size, void* d_ws, size_t ws_size,
                              hipStream_t stream)
{
    const float* f1 = (const float*)d_in[0];
    const float* f2 = (const float*)d_in[1];
    float* out = (float*)d_out;
    corr_kernel<<<dim3(NBLK), 192, 0, stream>>>(f1, f2, out);
}

// Round 22
// 212.197 us; speedup vs baseline: 1.2059x; 1.2059x over previous
//
#include <hip/hip_runtime.h>

#define B_   8
#define C_   96
#define H_   160
#define W_   320
#define ND   9
#define NDD  81
#define TH   16
#define TW   32                 // 8 px/thread
#define KC   8                  // channels per chunk (12 periods; period cost is per-chunk)
#define NCH  12
#define F2ROWS 18
#define F2STRIDE 44             // 40 payload + 4 pad cols (2-way bank aliasing only)
#define F2PLANE (F2ROWS*F2STRIDE)   // 792 dw per channel
#define BUFW (KC*F2PLANE)           // 6336 dw = 25344 B
#define LDSWORDS (2*BUFW)           // 50688 B -> 3 blocks/CU (9 waves), reg budget 170

#define AS1 __attribute__((address_space(1)))
#define AS3 __attribute__((address_space(3)))

__device__ __forceinline__ void gld16(const float* gp, float* lp) {
    // HBM/L2 -> LDS direct; LDS dest = wave-uniform base + lane*16
    __builtin_amdgcn_global_load_lds((const AS1 float*)gp,
                                     (AS3 float*)(unsigned long long)lp, 16, 0, 0);
}

__global__ __launch_bounds__(192, 2)
void corr_kernel(const float* __restrict__ f1g,
                 const float* __restrict__ f2g,
                 float* __restrict__ out)
{
    __shared__ float lds[LDSWORDS];

    const int tid  = threadIdx.x;
    const int wave = tid >> 6;
    const int lane = tid & 63;
    const int row  = lane >> 2;         // 0..15
    const int colb = (lane & 3) << 3;   // 0,8,16,24

    // XCD swizzle: 2400 = 8 XCDs x 300 (bijective); XCD owns batch b.
    const int bid  = blockIdx.x;
    const int ebid = (bid & 7) * 300 + (bid >> 3);
    const int b    = ebid / 300;
    const int t3   = ebid - b * 300;
    const int g    = t3 % 3;            // dh = 3g + wave
    const int tile = t3 / 3;
    const int by   = tile / 10, bx = tile - by * 10;
    const int x0 = bx * TW, y0 = by * TH;
    const int HWi  = H_ * W_;
    const int r0   = y0 + 3 * g - 4;

    const float* f1b = f1g + (size_t)b * C_ * HWi;
    const float* f2b = f2g + (size_t)b * C_ * HWi;
    const float* f1p = f1b + (y0 + row) * W_ + x0 + colb;

    // f2 staging maps (seg s -> lds dw 4s; r=s/11, c4=s%11; c4==10 = pad col)
    int soW, soT; bool ppW, ppT;
    {
        int s  = (wave << 6) + lane;
        int r  = s / 11, c4 = s - 11 * r;
        int gy = r0 + r, gx = x0 - 4 + (c4 << 2);
        ppW = (c4 < 10) & (gy >= 0) & (gy < H_) & (gx >= 0) & (gx <= W_ - 4);
        soW = gy * W_ + gx;
        s  = 192 + lane;
        r  = s / 11; c4 = s - 11 * r;
        gy = r0 + r; gx = x0 - 4 + (c4 << 2);
        ppT = (wave == 2) & (lane < 6) & (c4 < 10) &
              (gy >= 0) & (gy < H_) & (gx >= 0) & (gx <= W_ - 4);
        soT = gy * W_ + gx;
    }
    const int partoff = wave << 8;

    const int o0 = (row + wave) * F2STRIDE + colb;

    // stage chunk cb..cb+7: 8-9 DMAs per wave (one barrier period per 8 channels)
    auto stage = [&](int cb, int bufb) {
#pragma unroll
        for (int c = 0; c < KC; ++c) {
            const float* gsrc = f2b + (cb + c) * HWi;
            float* l = &lds[bufb + c * F2PLANE];
            if (ppW) gld16(gsrc + soW, l + partoff);
            if (ppT) gld16(gsrc + soT, l + 768);
        }
    };

    // ---- accumulators ----
    float4 accA0, accA1, accA2, accA3, accA4, accA5, accA6, accA7, accA8;
    float4 accB0, accB1, accB2, accB3, accB4, accB5, accB6, accB7, accB8;
    accA0=accA1=accA2=accA3=accA4=accA5=accA6=accA7=accA8 = make_float4(0.f,0.f,0.f,0.f);
    accB0=accB1=accB2=accB3=accB4=accB5=accB6=accB7=accB8 = make_float4(0.f,0.f,0.f,0.f);

    // f1 halves: P = channels cb..cb+3 (loaded before stage), Q = cb+4..cb+7
    // (issued after stage, consumed ~4 COMPCs later) — caps max-live regs.
    float4 PA0, PA1, PA2, PA3, PB0, PB1, PB2, PB3;
    float4 QA0, QA1, QA2, QA3, QB0, QB1, QB2, QB3;

#define F1LOADP(cb) {                                             \
        PA0 = *(const float4*)(f1p + (cb) * HWi);                 \
        PB0 = *(const float4*)(f1p + (cb) * HWi + 4);             \
        PA1 = *(const float4*)(f1p + ((cb)+1) * HWi);             \
        PB1 = *(const float4*)(f1p + ((cb)+1) * HWi + 4);         \
        PA2 = *(const float4*)(f1p + ((cb)+2) * HWi);             \
        PB2 = *(const float4*)(f1p + ((cb)+2) * HWi + 4);         \
        PA3 = *(const float4*)(f1p + ((cb)+3) * HWi);             \
        PB3 = *(const float4*)(f1p + ((cb)+3) * HWi + 4); }
#define F1LOADQ(cb) {                                             \
        QA0 = *(const float4*)(f1p + (cb) * HWi);                 \
        QB0 = *(const float4*)(f1p + (cb) * HWi + 4);             \
        QA1 = *(const float4*)(f1p + ((cb)+1) * HWi);             \
        QB1 = *(const float4*)(f1p + ((cb)+1) * HWi + 4);         \
        QA2 = *(const float4*)(f1p + ((cb)+2) * HWi);             \
        QB2 = *(const float4*)(f1p + ((cb)+2) * HWi + 4);         \
        QA3 = *(const float4*)(f1p + ((cb)+3) * HWi);             \
        QB3 = *(const float4*)(f1p + ((cb)+3) * HWi + 4); }

#define STEPD(A, P, e0, e1, e2, e3)                          \
        A.x = fmaf(P.x, e0, A.x);                            \
        A.y = fmaf(P.y, e1, A.y);                            \
        A.z = fmaf(P.z, e2, A.z);                            \
        A.w = fmaf(P.w, e3, A.w);

#define COMPC(c, RB, PA, PB) {                                                    \
        const float4 q0 = *(const float4*)&lds[(RB) + c * F2PLANE + o0];          \
        const float4 q1 = *(const float4*)&lds[(RB) + c * F2PLANE + o0 + 4];      \
        const float4 q2 = *(const float4*)&lds[(RB) + c * F2PLANE + o0 + 8];      \
        const float4 q3 = *(const float4*)&lds[(RB) + c * F2PLANE + o0 + 12];     \
        const float w[16] = {q0.x,q0.y,q0.z,q0.w,q1.x,q1.y,q1.z,q1.w,            \
                             q2.x,q2.y,q2.z,q2.w,q3.x,q3.y,q3.z,q3.w};           \
        STEPD(accA0, PA, w[0], w[1], w[2], w[3])                                  \
        STEPD(accB0, PB, w[4], w[5], w[6], w[7])                                  \
        STEPD(accA1, PA, w[1], w[2], w[3], w[4])                                  \
        STEPD(accB1, PB, w[5], w[6], w[7], w[8])                                  \
        STEPD(accA2, PA, w[2], w[3], w[4], w[5])                                  \
        STEPD(accB2, PB, w[6], w[7], w[8], w[9])                                  \
        STEPD(accA3, PA, w[3], w[4], w[5], w[6])                                  \
        STEPD(accB3, PB, w[7], w[8], w[9], w[10])                                 \
        STEPD(accA4, PA, w[4], w[5], w[6], w[7])                                  \
        STEPD(accB4, PB, w[8], w[9], w[10], w[11])                                \
        STEPD(accA5, PA, w[5], w[6], w[7], w[8])                                  \
        STEPD(accB5, PB, w[9], w[10], w[11], w[12])                               \
        STEPD(accA6, PA, w[6], w[7], w[8], w[9])                                  \
        STEPD(accB6, PB, w[10], w[11], w[12], w[13])                              \
        STEPD(accA7, PA, w[7], w[8], w[9], w[10])                                 \
        STEPD(accB7, PB, w[11], w[12], w[13], w[14])                              \
        STEPD(accA8, PA, w[8], w[9], w[10], w[11])                                \
        STEPD(accB8, PB, w[12], w[13], w[14], w[15])                              \
    }

    // one-time zero (OOB/pad slots never DMA'd; payload rewritten every chunk)
    for (int t = tid; t < LDSWORDS; t += 192) lds[t] = 0.f;
    __syncthreads();
    stage(0, 0);                          // chunk 0 -> buf 0

#pragma unroll 1
    for (int k = 0; k < NCH; ++k) {
        const int cb = KC * k;
        __syncthreads();                  // chunk-k DMA drained (issued 1 chunk ago)
        F1LOADP(cb)                       // f1 first half BEFORE next DMAs
        if (k + 1 < NCH) stage(KC * (k + 1), ((k + 1) & 1) * BUFW);
        F1LOADQ(cb + 4)                   // second half: consumed ~4 COMPCs later
        __builtin_amdgcn_sched_barrier(0);
        const int rb = (k & 1) * BUFW;
        COMPC(0, rb, PA0, PB0) COMPC(1, rb, PA1, PB1)
        COMPC(2, rb, PA2, PB2) COMPC(3, rb, PA3, PB3)
        COMPC(4, rb, QA0, QB0) COMPC(5, rb, QA1, QB1)
        COMPC(6, rb, QA2, QB2) COMPC(7, rb, QA3, QB3)
    }

    // ---- epilogue: dh = 3g + wave; out[b, dh*9+d, y0+row, x0+colb..+7] ----
    const int dh = 3 * g + wave;
    const int gy = y0 + row;
    const int gx = x0 + colb;
#define STORED(d) {                                                                 \
        float* op_ = out + (size_t)((b * NDD + dh * ND + d) * H_ + gy) * W_ + gx;   \
        *(float4*)op_ = accA##d;                                                    \
        *(float4*)(op_ + 4) = accB##d; }
    STORED(0) STORED(1) STORED(2) STORED(3) STORED(4)
    STORED(5) STORED(6) STORED(7) STORED(8)
}

extern "C" void kernel_launch(void* const* d_in, const int* in_sizes, int n_in,
                              void* d_out, int out_size, void* d_ws, size_t ws_size,
                              hipStream_t stream)
{
    const float* f1 = (const float*)d_in[0];
    const float* f2 = (const float*)d_in[1];
    float* out = (float*)d_out;
    corr_kernel<<<dim3(2400), 192, 0, stream>>>(f1, f2, out);
}